// Round 1
// baseline (172.027 us; speedup 1.0000x reference)
//
#include <hip/hip_runtime.h>
#include <hip/hip_bf16.h>

typedef unsigned short u16;
typedef unsigned int u32;
typedef __attribute__((ext_vector_type(4))) float f32x4;
typedef __attribute__((ext_vector_type(8))) u16 u16x8;
typedef __attribute__((ext_vector_type(8))) __bf16 bf16x8;

#define B_ 32
#define T_ 2048
#define MID_ 1024
#define TOPIC_ 512
#define H_ 256

// fp32 -> bf16 RNE
static __device__ __forceinline__ u16 f2bf(float x) {
    u32 u = __float_as_uint(x);
    u = (u + 0x7FFFu + ((u >> 16) & 1u)) >> 16;
    return (u16)u;
}

// ---------------- prep kernels ----------------

// enc_out[b][h] = Ua_b[h] + sum_d enc[b][d] * Ua_w[h][d]
__global__ __launch_bounds__(256) void k_enc(const float* __restrict__ enc,
                                             const float* __restrict__ Ua_w,
                                             const float* __restrict__ Ua_b,
                                             float* __restrict__ enc_out) {
    __shared__ float es[TOPIC_];
    const int b = blockIdx.x, tid = threadIdx.x;
    es[tid]       = enc[b * TOPIC_ + tid];
    es[tid + 256] = enc[b * TOPIC_ + 256 + tid];
    __syncthreads();
    const float* ua = Ua_w + (size_t)tid * TOPIC_;
    float s = Ua_b[tid];
    #pragma unroll 4
    for (int d = 0; d < TOPIC_; d += 4) {
        f32x4 u = *(const f32x4*)(ua + d);
        s += u[0] * es[d] + u[1] * es[d + 1] + u[2] * es[d + 2] + u[3] * es[d + 3];
    }
    enc_out[b * H_ + tid] = s;
}

// vsum = sum_h v_w[h]
__global__ void k_vsum(const float* __restrict__ v_w, float* __restrict__ vsum) {
    const int lane = threadIdx.x;  // 64 threads
    float s = v_w[lane] + v_w[lane + 64] + v_w[lane + 128] + v_w[lane + 192];
    #pragma unroll
    for (int m = 32; m; m >>= 1) s += __shfl_xor(s, m, 64);
    if (lane == 0) *vsum = s;
}

// Wa (fp32 [256][1024]) -> bf16, K-step-major layout [ks=32][h=256][kk=32]
__global__ __launch_bounds__(256) void k_wacvt(const float* __restrict__ Wa,
                                               u16* __restrict__ wa16s) {
    const int e0 = blockIdx.x * 1024 + threadIdx.x;
    #pragma unroll
    for (int i = 0; i < 4; ++i) {
        const int e = e0 + 256 * i;        // 0..262143, e = h*1024 + k
        const int h = e >> 10, k = e & 1023;
        wa16s[(k >> 5) * (H_ * 32) + h * 32 + (k & 31)] = f2bf(Wa[e]);
    }
}

// ---------------- logits: a[b,t] = sum_h v[h]*tanh(enc_out[b][h] + dec[b,t,:]·Wa[h,:]) ----------------
// 64 rows per workgroup, 4 waves; each wave: 16 rows x 256 cols via 16 MFMA col-tiles.
__global__ __launch_bounds__(256) void k_logits(const float* __restrict__ dec,
                                                const int* __restrict__ masks,
                                                const float* __restrict__ enc_out,
                                                const float* __restrict__ v_w,
                                                const float* __restrict__ vsum_p,
                                                const u16* __restrict__ wa16s,
                                                float* __restrict__ a_out) {
    // pad stride 40 bf16 (80 B): lanes 0..15 at stride 80B -> 2-way bank alias (free)
    __shared__ u16 wa_s[H_ * 40];
    __shared__ float encs[H_];
    __shared__ float vs[H_];

    const int tid = threadIdx.x;
    const int wave = tid >> 6, lane = tid & 63;
    const int row_lane = lane & 15, kgrp = lane >> 4;
    const int r0 = blockIdx.x * 64;          // flattened (b*T + t) row base
    const int b = r0 >> 11;                  // 64 | 2048 so whole block is one b

    encs[tid] = enc_out[(b << 8) + tid];
    vs[tid] = v_w[tid];

    f32x4 acc[16];
    const f32x4 z = {0.f, 0.f, 0.f, 0.f};
    #pragma unroll
    for (int i = 0; i < 16; ++i) acc[i] = z;

    const float* arow = dec + (size_t)(r0 + wave * 16 + row_lane) * MID_ + kgrp * 8;
    const u16* wsrc = wa16s + tid * 32;

    for (int ks = 0; ks < 32; ++ks) {
        __syncthreads();  // protect previous iteration's LDS reads
        // stage Wa slice [256 h][32 k] (thread tid = row h), coalesced 64B/thread
        u16x8 w0 = *(const u16x8*)(wsrc);
        u16x8 w1 = *(const u16x8*)(wsrc + 8);
        u16x8 w2 = *(const u16x8*)(wsrc + 16);
        u16x8 w3 = *(const u16x8*)(wsrc + 24);
        wsrc += H_ * 32;
        u16* dst = &wa_s[tid * 40];
        *(u16x8*)(dst) = w0;      *(u16x8*)(dst + 8) = w1;
        *(u16x8*)(dst + 16) = w2; *(u16x8*)(dst + 24) = w3;
        // A fragment: dec[r0+16w+row_lane][ks*32 + kgrp*8 + 0..7], fp32 -> bf16
        f32x4 a0 = *(const f32x4*)(arow);
        f32x4 a1 = *(const f32x4*)(arow + 4);
        arow += 32;
        __syncthreads();
        u16x8 au;
        #pragma unroll
        for (int i = 0; i < 4; ++i) { au[i] = f2bf(a0[i]); au[4 + i] = f2bf(a1[i]); }
        bf16x8 af = __builtin_bit_cast(bf16x8, au);
        #pragma unroll
        for (int tile = 0; tile < 16; ++tile) {
            bf16x8 bf = *(const bf16x8*)&wa_s[(tile * 16 + row_lane) * 40 + kgrp * 8];
            acc[tile] = __builtin_amdgcn_mfma_f32_16x16x32_bf16(af, bf, acc[tile], 0, 0, 0);
        }
    }

    // epilogue: part[j] = sum over this lane's 16 cols of v*tanh(enc + c)
    float part0 = 0.f, part1 = 0.f, part2 = 0.f, part3 = 0.f;
    #pragma unroll
    for (int tile = 0; tile < 16; ++tile) {
        const int col = tile * 16 + row_lane;
        const float e = encs[col];
        const float vv = vs[col];
        part0 += vv * tanhf(e + acc[tile][0]);
        part1 += vv * tanhf(e + acc[tile][1]);
        part2 += vv * tanhf(e + acc[tile][2]);
        part3 += vv * tanhf(e + acc[tile][3]);
    }
    // reduce over the 16 lanes sharing kgrp (lane bits 0..3)
    #pragma unroll
    for (int m = 1; m < 16; m <<= 1) {
        part0 += __shfl_xor(part0, m, 64);
        part1 += __shfl_xor(part1, m, 64);
        part2 += __shfl_xor(part2, m, 64);
        part3 += __shfl_xor(part3, m, 64);
    }
    if (row_lane == 0) {
        const float nvs = -(*vsum_p);  // masked logit = -sum(v)  (tanh(-inf) = -1)
        float p[4] = {part0, part1, part2, part3};
        #pragma unroll
        for (int j = 0; j < 4; ++j) {
            const int row = r0 + wave * 16 + kgrp * 4 + j;  // C layout: row=(l>>4)*4+j
            const int t = row & (T_ - 1);
            a_out[row] = masks[(b << 11) + t] ? p[j] : nvs;
        }
    }
}

// ---------------- softmax over T per b ----------------
__global__ __launch_bounds__(256) void k_softmax(const float* __restrict__ a_buf,
                                                 float* __restrict__ r_buf) {
    const int b = blockIdx.x, tid = threadIdx.x;
    const int wave = tid >> 6, lane = tid & 63;
    __shared__ float wred[4];
    float l[8];
    float m = -1e30f;
    #pragma unroll
    for (int i = 0; i < 8; ++i) {
        l[i] = a_buf[b * T_ + tid + 256 * i];
        m = fmaxf(m, l[i]);
    }
    #pragma unroll
    for (int msk = 32; msk; msk >>= 1) m = fmaxf(m, __shfl_xor(m, msk, 64));
    if (lane == 0) wred[wave] = m;
    __syncthreads();
    m = fmaxf(fmaxf(wred[0], wred[1]), fmaxf(wred[2], wred[3]));
    __syncthreads();
    float e[8];
    float s = 0.f;
    #pragma unroll
    for (int i = 0; i < 8; ++i) { e[i] = expf(l[i] - m); s += e[i]; }
    #pragma unroll
    for (int msk = 32; msk; msk >>= 1) s += __shfl_xor(s, msk, 64);
    if (lane == 0) wred[wave] = s;
    __syncthreads();
    s = wred[0] + wred[1] + wred[2] + wred[3];
    const float inv = 1.0f / s;
    #pragma unroll
    for (int i = 0; i < 8; ++i) r_buf[b * T_ + tid + 256 * i] = e[i] * inv;
}

// ---------------- weighted sum: partials[b][tc][m] = sum_{t in chunk} r[b,t]*dec[b,t,m] ----------------
__global__ __launch_bounds__(256) void k_wsum(const float* __restrict__ dec,
                                              const float* __restrict__ r_buf,
                                              float* __restrict__ partials) {
    const int tc = blockIdx.x, b = blockIdx.y, tid = threadIdx.x;
    const float* base = dec + ((size_t)b * T_ + tc * 128) * MID_ + tid * 4;
    const float* rp = r_buf + b * T_ + tc * 128;
    f32x4 acc = {0.f, 0.f, 0.f, 0.f};
    #pragma unroll 4
    for (int i = 0; i < 128; ++i) {
        const float w = rp[i];
        f32x4 d4 = *(const f32x4*)(base + (size_t)i * MID_);
        acc += d4 * w;
    }
    *(f32x4*)(partials + ((b * 16 + tc) * MID_) + tid * 4) = acc;
}

// out[b][m] = sum_tc partials[b][tc][m]
__global__ __launch_bounds__(256) void k_final(const float* __restrict__ partials,
                                               float* __restrict__ out) {
    const int idx = blockIdx.x * 256 + threadIdx.x;  // 0..32767
    const int b = idx >> 10, mcol = idx & 1023;
    float s = 0.f;
    #pragma unroll
    for (int tc = 0; tc < 16; ++tc) s += partials[(b * 16 + tc) * MID_ + mcol];
    out[idx] = s;
}

extern "C" void kernel_launch(void* const* d_in, const int* in_sizes, int n_in,
                              void* d_out, int out_size, void* d_ws, size_t ws_size,
                              hipStream_t stream) {
    const float* enc   = (const float*)d_in[0];
    const float* dec   = (const float*)d_in[1];
    const int*   masks = (const int*)d_in[2];
    const float* Ua_w  = (const float*)d_in[3];
    const float* Ua_b  = (const float*)d_in[4];
    const float* Wa_w  = (const float*)d_in[5];
    const float* v_w   = (const float*)d_in[6];
    float* out = (float*)d_out;

    char* ws = (char*)d_ws;
    float* enc_out  = (float*)(ws + 0);        // 32 KB
    float* vsum     = (float*)(ws + 32768);    // 4 B (padded)
    u16*   wa16s    = (u16*)(ws + 65536);      // 512 KB
    float* a_buf    = (float*)(ws + 589824);   // 256 KB
    float* r_buf    = (float*)(ws + 851968);   // 256 KB
    float* partials = (float*)(ws + 1114112);  // 2 MB

    k_enc<<<dim3(B_), dim3(256), 0, stream>>>(enc, Ua_w, Ua_b, enc_out);
    k_vsum<<<dim3(1), dim3(64), 0, stream>>>(v_w, vsum);
    k_wacvt<<<dim3(256), dim3(256), 0, stream>>>(Wa_w, wa16s);
    k_logits<<<dim3((B_ * T_) / 64), dim3(256), 0, stream>>>(dec, masks, enc_out, v_w,
                                                             vsum, wa16s, a_buf);
    k_softmax<<<dim3(B_), dim3(256), 0, stream>>>(a_buf, r_buf);
    k_wsum<<<dim3(16, B_), dim3(256), 0, stream>>>(dec, r_buf, partials);
    k_final<<<dim3(128), dim3(256), 0, stream>>>(partials, out);
}